// Round 17
// baseline (168.413 us; speedup 1.0000x reference)
//
#include <hip/hip_runtime.h>
#include <stdint.h>

#define TT 2048
#define DD 1024
#define HH 16
#define LDP 4368   // concat width: 3072 qkv | 64 w1 | 64 w2 | 64 r1 | 64 r2 | 1024 memv | 16 gate
#define SCH 32     // scan chunk length
#define SNC (TT/SCH)  // 64 chunks per sequence

using bf16x8 = __attribute__((ext_vector_type(8))) __bf16;
using u16x8  = __attribute__((ext_vector_type(8))) unsigned short;
using f32x4  = __attribute__((ext_vector_type(4))) float;

__device__ __forceinline__ float bf2f(unsigned short u){
  unsigned int x = ((unsigned int)u) << 16;
  return __builtin_bit_cast(float, x);
}
__device__ __forceinline__ unsigned short f2bf(float f){
  unsigned int x = __builtin_bit_cast(unsigned int, f);
  x += 0x7fffu + ((x >> 16) & 1u);
  return (unsigned short)(x >> 16);
}
__device__ __forceinline__ float sigmoidf_(float x){ return 1.0f/(1.0f+__expf(-x)); }

// global -> LDS direct (16B/lane). LDS base must be wave-uniform; HW adds lane*16.
__device__ __forceinline__ void gload_lds16(const void* g, void* l){
  auto gp = (const __attribute__((address_space(1))) unsigned int*)(uintptr_t)g;
  auto lp = (__attribute__((address_space(3))) unsigned int*)(unsigned int)(uintptr_t)l;
  __builtin_amdgcn_global_load_lds(gp, lp, 16, 0, 0);
}

// ---------------- exterior products + J6 map ----------------
__device__ __forceinline__ void ext6(const float* p, const float* q, float* L){
  L[0] = p[0]*q[1] - p[1]*q[0];
  L[1] = p[0]*q[2] - p[2]*q[0];
  L[2] = p[0]*q[3] - p[3]*q[0];
  L[3] = p[1]*q[2] - p[2]*q[1];
  L[4] = p[1]*q[3] - p[3]*q[1];
  L[5] = p[2]*q[3] - p[3]*q[2];
  const float n2 = L[0]*L[0]+L[1]*L[1]+L[2]*L[2]+L[3]*L[3]+L[4]*L[4]+L[5]*L[5];
  const float inv = 1.0f / fmaxf(sqrtf(n2), 1e-12f);
#pragma unroll
  for (int i = 0; i < 6; ++i) L[i] *= inv;
}

__device__ __forceinline__ void load4bf(const unsigned short* p, float* o){
  const ushort4 u = *(const ushort4*)p;
  o[0] = bf2f(u.x); o[1] = bf2f(u.y); o[2] = bf2f(u.z); o[3] = bf2f(u.w);
}

// ---------------- fused weight prep + x conversion ----------------
__global__ void prep_all_kernel(const float* __restrict__ qkv_w, const float* __restrict__ w1w,
                                const float* __restrict__ w2w, const float* __restrict__ r1w,
                                const float* __restrict__ r2w, const float* __restrict__ memv_w,
                                const float* __restrict__ memg_w, const float* __restrict__ out_w,
                                const float* __restrict__ qkv_b, const float* __restrict__ memv_b,
                                const float* __restrict__ memg_b, const float* __restrict__ x,
                                unsigned short* __restrict__ Wcat, float* __restrict__ bcat,
                                unsigned short* __restrict__ xb)
{
  const int blk = blockIdx.x;
  if (blk < 5392) {
    const int idx = blk*256 + threadIdx.x;
    {
      const int row = idx >> 8, c4 = (idx & 255)*4;
      const float* src; int r;
      if      (row < 3072) { src = qkv_w;  r = row; }
      else if (row < 3136) { src = w1w;    r = row-3072; }
      else if (row < 3200) { src = w2w;    r = row-3136; }
      else if (row < 3264) { src = r1w;    r = row-3200; }
      else if (row < 3328) { src = r2w;    r = row-3264; }
      else if (row < 4352) { src = memv_w; r = row-3328; }
      else if (row < 4368) { src = memg_w; r = row-4352; }
      else                 { src = out_w;  r = row-4368; }
      const float4 v = *(const float4*)(src + (size_t)r*1024 + c4);
      ushort4 o; o.x=f2bf(v.x); o.y=f2bf(v.y); o.z=f2bf(v.z); o.w=f2bf(v.w);
      *(ushort4*)(Wcat + (size_t)row*1024 + c4) = o;
    }
    if (idx < 4368) {
      float v;
      if      (idx < 3072) v = qkv_b[idx];
      else if (idx < 3328) v = 0.f;
      else if (idx < 4352) v = memv_b[idx-3328];
      else                 v = memg_b[idx-4352];
      bcat[idx] = v;
    }
  } else {
    const int idx = (blk - 5392)*256 + threadIdx.x;   // 4096*256 exact, 4 elems each
    const float4 v = ((const float4*)x)[idx];
    ushort4 o; o.x=f2bf(v.x); o.y=f2bf(v.y); o.z=f2bf(v.z); o.w=f2bf(v.w);
    ((ushort4*)xb)[idx] = o;
  }
}

// ---------------- GEMM: C[M,N] = A[M,K] * Bt[N,K]^T + bias ----------------
// 3-buffer (48KB), counted vmcnt(4) steady-state (round-9-proven).
// bf16 path: epilogue staged through LDS (row-XOR-swizzled) for coalesced 16B stores.
// V-column tiles (n0 in [2048,3072), VTout != null) store TRANSPOSED to VT instead of P.
template<bool OUTF32>
__global__ __launch_bounds__(256, 3)
void gemm_bt_kernel(const unsigned short* __restrict__ A, int lda,
                    const unsigned short* __restrict__ Bt, int ldb,
                    const float* __restrict__ bias,
                    void* __restrict__ Cout, int ldc, int N, int K,
                    unsigned short* __restrict__ VTout)
{
  __shared__ unsigned short smem[24576];   // A: 3 bufs @ 8KB | B: 3 bufs @ 8KB (byte 24576+)
  const int tid = threadIdx.x;
  const int w = tid >> 6, lane = tid & 63;
  const int l15 = lane & 15, l4 = lane >> 4;
  const int m0 = blockIdx.x * 128;
  const int n0 = blockIdx.y * 128;
  const int wr = (w >> 1) * 64, wc = (w & 1) * 64;

  const f32x4 zero = {0.f,0.f,0.f,0.f};
  f32x4 acc[4][4];
#pragma unroll
  for (int i = 0; i < 4; ++i)
#pragma unroll
    for (int j = 0; j < 4; ++j) acc[i][j] = zero;

  const int srow = lane >> 2;
  const int k8   = (lane & 3) * 8;

  auto stage = [&](int k0, int buf) {
#pragma unroll
    for (int q = 0; q < 4; ++q) {
      const int c = q*4 + w;                 // 0..15 chunk of 1KB
      const int rloc = (c & 7)*16 + srow;
      if (c < 8) {
        gload_lds16(A + (size_t)(m0 + rloc)*lda + k0 + k8,
                    (char*)smem + buf*8192 + (c&7)*1024);
      } else {
        int nrow = n0 + rloc; if (nrow >= N) nrow = N - 1;
        gload_lds16(Bt + (size_t)nrow*ldb + k0 + k8,
                    (char*)smem + 24576 + buf*8192 + (c&7)*1024);
      }
    }
  };

  stage(0, 0);
  if (K > 32) stage(32, 1);

  int ti = 0;
  for (int k0 = 0; k0 < K; k0 += 32, ++ti) {
    // stage(ti) must be retired; stage(ti+1) (4 loads/lane) may remain in flight
    if (k0 + 32 < K) { asm volatile("s_waitcnt vmcnt(4)" ::: "memory"); }
    else             { asm volatile("s_waitcnt vmcnt(0)" ::: "memory"); }
    __builtin_amdgcn_s_barrier();
    // overwrites buf (ti-1)%3: its readers issued MFMAs (lgkm-drained) before this barrier
    if (k0 + 64 < K) stage(k0 + 64, (ti + 2) % 3);

    const int cur = ti % 3;
    bf16x8 af[4], bfr[4];
#pragma unroll
    for (int i = 0; i < 4; ++i) {
      af[i]  = *reinterpret_cast<const bf16x8*>((const char*)smem + cur*8192
                 + (wr + i*16 + l15)*64 + l4*16);
      bfr[i] = *reinterpret_cast<const bf16x8*>((const char*)smem + 24576 + cur*8192
                 + (wc + i*16 + l15)*64 + l4*16);
    }
#pragma unroll
    for (int i = 0; i < 4; ++i)
#pragma unroll
      for (int j = 0; j < 4; ++j)
        acc[i][j] = __builtin_amdgcn_mfma_f32_16x16x32_bf16(af[i], bfr[j], acc[i][j], 0, 0, 0);
  }

  if (OUTF32) {
#pragma unroll
    for (int i = 0; i < 4; ++i) {
      const int rowb = m0 + wr + i*16 + l4*4;
#pragma unroll
      for (int j = 0; j < 4; ++j) {
        const int col = n0 + wc + j*16 + l15;
        if (col < N) {
          const float bv = bias ? bias[col] : 0.0f;
#pragma unroll
          for (int r = 0; r < 4; ++r)
            ((float*)Cout)[(size_t)(rowb + r)*ldc + col] = acc[i][j][r] + bv;
        }
      }
    }
  } else {
    // all waves' LDS reads retired before smem is repurposed for the C tile
    __syncthreads();
    const bool isV = (VTout != nullptr) && (n0 >= 2048) && (n0 < 3072);
    // stage C tile (+bias) into smem as [128][128] bf16, row-XOR-swizzled:
    // byte(row,col) = row*256 + ((col*2) ^ ((row&15)<<4))
#pragma unroll
    for (int i = 0; i < 4; ++i) {
      const int rloc = wr + i*16 + l4*4;
#pragma unroll
      for (int j = 0; j < 4; ++j) {
        const int col = wc + j*16 + l15;
        const float bv = bias ? bias[n0 + col] : 0.0f;
#pragma unroll
        for (int r = 0; r < 4; ++r) {
          const int row = rloc + r;
          const unsigned byte = (unsigned)row*256u
                              + (((unsigned)col*2u) ^ (((unsigned)row & 15u) << 4));
          *(unsigned short*)((char*)smem + byte) = f2bf(acc[i][j][r] + bv);
        }
      }
    }
    __syncthreads();
    if (!isV) {
#pragma unroll
      for (int p = 0; p < 8; ++p) {
        const int idx = p*256 + tid;          // 0..2047
        const int row = idx >> 4;             // 0..127
        const int c8  = (idx & 15) * 8;       // element 0..120
        if (n0 + c8 + 8 <= N) {
          // element c8's byte offset is c8*2 (16-aligned); swizzle preserves 16B blocks
          const unsigned byte = (unsigned)row*256u
                              + (((unsigned)(c8*2)) ^ (((unsigned)row & 15u) << 4));
          *(u16x8*)((unsigned short*)Cout + (size_t)(m0 + row)*ldc + n0 + c8) =
              *(const u16x8*)((const char*)smem + byte);
        }
      }
    } else {
      // transposed store: VT[vbase + d2][t0 + tl] = tile[tl][d2], t0 = within-batch offset
      const int vbase = ((m0 >> 11)*HH + ((n0 - 2048) >> 6)) * 64;
      const int t0 = m0 & (TT - 1);
      for (int it = 0; it < 64; ++it) {
        const int i2 = it*256 + tid;        // 0..16383
        const int d2 = i2 >> 7;             // 0..127  (tile column)
        const int tl = i2 & 127;            // 0..127  (tile row = t offset)
        const unsigned byte = (unsigned)tl*256u
                            + (((unsigned)d2*2u) ^ (((unsigned)tl & 15u) << 4));
        VTout[(size_t)(vbase + d2)*TT + t0 + tl] =
            *(const unsigned short*)((const char*)smem + byte);
      }
    }
  }
}

// ---------------- flash attention (+ fused scanA blocks) ----------------
// Blocks [0,512): paired q-tiles {pi,31-pi}, swapped-QK, KVBLK=128, XCD-grouped (round-15).
// Blocks [512,1024): scanA — 4 chunks per block, one per wave (per-wave LDS overlay on Ks).
// seqo is written as bf16.
__global__ __launch_bounds__(256, 2)
void attn_kernel(const unsigned short* __restrict__ P,
                 const unsigned short* __restrict__ VT,
                 unsigned short* __restrict__ seqo,
                 const float* __restrict__ decay_logits,
                 float* __restrict__ E)
{
  __shared__ unsigned short Ks[2][128*64];   // [k-row][64 d], rows XOR-swizzled
  __shared__ unsigned short Vs[2][64*128];   // [d-row][128 k], rows XOR-swizzled
  __shared__ unsigned short Pls[4][16*128];  // per-wave [q][128 k], XOR-swizzled

  const int tid = threadIdx.x;
  const int w = tid >> 6, lane = tid & 63;
  const int l15 = lane & 15, l4 = lane >> 4;

  if (blockIdx.x >= 512) {
    // ---------- scanA: per-chunk E (one chunk per wave, SCH=32) ----------
    float* jwS = (float*)Ks + (size_t)w * SCH * 6;   // per-wave [SCH][6] overlay
    const int chunk = (blockIdx.x - 512)*4 + w;      // 0..2047 = 32 s * 64 chunks
    const int s = chunk >> 6, c = chunk & (SNC-1);
    const int b_ = s >> 4, h = s & (HH-1);
    if (lane < SCH) {
      const int t = c*SCH + lane;
      const size_t row = (size_t)(b_*TT + t)*LDP;
      float w1[4], w2[4];
      if (t > 0) load4bf(P + row - LDP + 3072 + h*4, w1);
      else { w1[0]=w1[1]=w1[2]=w1[3]=0.f; }
      load4bf(P + row + 3136 + h*4, w2);
      float wl[6];
      ext6(w1, w2, wl);
      jwS[lane*6+0]= wl[5]; jwS[lane*6+1]=-wl[4]; jwS[lane*6+2]= wl[3];
      jwS[lane*6+3]= wl[2]; jwS[lane*6+4]=-wl[1]; jwS[lane*6+5]= wl[0];
    }
    // same-wave LDS handoff (writes visible to this wave's lanes)
    asm volatile("s_waitcnt lgkmcnt(0)" ::: "memory");

    const int i = lane & 7, j = lane >> 3;
    const int ic = i < 6 ? i : 0, jc = j < 6 ? j : 0;
    const float d = sigmoidf_(decay_logits[h]);
    float e = 0.f;
    for (int t = 0; t < SCH; ++t)
      e = d*(e + jwS[t*6+ic]*jwS[t*6+jc]);
    if (i < 6 && j < 6) E[(size_t)chunk*36 + j*6 + i] = e;
    return;
  }

  // ---------- attention ----------
  // XCD-grouped decode (T1): n -> (pi, h, b); 4 (b,h) groups per XCD
  const int n = blockIdx.x;
  const int xcd = n & 7, slot = n >> 3;
  const int grp = slot >> 4, pi = slot & 15;
  const int g = grp*8 + xcd;
  const int h = g & 15, b = g >> 4;

  auto stage = [&](int kt, int bufsel) {
#pragma unroll
    for (int q2 = 0; q2 < 4; ++q2) {
      const int idx = q2*256 + tid;
      {
        // K tile: 128 rows x 128B; element d at byte (d*2)^((r&7)<<4)
        const int r = idx >> 3;                          // 0..127
        const int cb = ((idx & 7)*16) ^ ((r & 7) << 4);  // swizzled source column byte
        gload_lds16(P + (size_t)(b*TT + kt*128 + r)*LDP + 1024 + h*64 + (cb >> 1),
                    (char*)Ks[bufsel] + q2*4096 + w*1024);
      }
      {
        // V tile: 64 rows x 256B; element k at byte (k*2)^((r&7)<<4)
        const int r = idx >> 4;                          // 0..63
        const int cb = ((idx & 15)*16) ^ ((r & 7) << 4); // swizzled source column byte
        gload_lds16(VT + (size_t)((b*HH + h)*64 + r)*TT + kt*128 + (cb >> 1),
                    (char*)Vs[bufsel] + q2*4096 + w*1024);
      }
    }
  };

  const f32x4 zero = {0.f,0.f,0.f,0.f};
  const unsigned xorb = ((unsigned)(l15 & 7u)) << 4;

  for (int rep = 0; rep < 2; ++rep) {
    const int qt = rep == 0 ? pi : 31 - pi;
    const int qbase = qt * 64;
    const int qrow = qbase + w*16 + l15;   // this lane's q-row
    const int nt = (qt >> 1) + 1;          // ceil((qt+1)/2) 128-wide k-tiles

    bf16x8 qa[2];
    {
      const size_t base = (size_t)(b*TT + qbase + w*16 + l15)*LDP + h*64 + l4*8;
      qa[0] = *reinterpret_cast<const bf16x8*>(P + base);
      qa[1] = *reinterpret_cast<const bf16x8*>(P + base + 32);
    }

    f32x4 o[4];
#pragma unroll
    for (int d = 0; d < 4; ++d) o[d] = zero;
    float mrow = -1e30f;
    float lrow = 0.f;

    stage(0, 0);
    asm volatile("s_waitcnt vmcnt(0)" ::: "memory");
    __builtin_amdgcn_s_barrier();

    for (int kt = 0; kt < nt; ++kt) {
      const int cur = kt & 1;
      if (kt + 1 < nt) stage(kt + 1, cur ^ 1);   // loads fly under this iteration's compute

      // ---- QK^T swapped: s[kk] = S^T, lane holds k = kk*16 + l4*4 + j for q = qrow ----
      f32x4 s[8];
#pragma unroll
      for (int kk = 0; kk < 8; ++kk) {
        f32x4 a = zero;
#pragma unroll
        for (int c = 0; c < 2; ++c) {
          const unsigned kbyte = (unsigned)((kk*16 + l15)*128)
                               + (((unsigned)(c*64 + l4*16)) ^ xorb);
          const bf16x8 kb = *reinterpret_cast<const bf16x8*>((const char*)Ks[cur] + kbyte);
          a = __builtin_amdgcn_mfma_f32_16x16x32_bf16(kb, qa[c], a, 0, 0, 0);
        }
        s[kk] = a;
      }

      if (kt == nt - 1) {   // diagonal-spanning tile (always the last one)
#pragma unroll
        for (int kk = 0; kk < 8; ++kk)
#pragma unroll
          for (int j = 0; j < 4; ++j) {
            const int kcol = kt*128 + kk*16 + l4*4 + j;
            s[kk][j] = (kcol <= qrow) ? s[kk][j]*0.125f : -1e30f;
          }
      } else {
#pragma unroll
        for (int kk = 0; kk < 8; ++kk)
#pragma unroll
          for (int j = 0; j < 4; ++j) s[kk][j] *= 0.125f;
      }

      // ---- online softmax, lane-local row (row spread over 4 lanes: xor16/xor32) ----
      float am[8];
#pragma unroll
      for (int kk = 0; kk < 8; ++kk)
        am[kk] = fmaxf(fmaxf(s[kk][0], s[kk][1]), fmaxf(s[kk][2], s[kk][3]));
      float tmax = fmaxf(fmaxf(fmaxf(am[0], am[1]), fmaxf(am[2], am[3])),
                         fmaxf(fmaxf(am[4], am[5]), fmaxf(am[6], am[7])));
      tmax = fmaxf(tmax, __shfl_xor(tmax, 16));
      tmax = fmaxf(tmax, __shfl_xor(tmax, 32));
      // T13 exact fast-path: tmax<=mrow for ALL rows -> corr==1, no rescale needed
      const bool skip = (__all(tmax <= mrow) != 0);
      const float mn = skip ? mrow : fmaxf(mrow, tmax);
      float lsum = 0.f;
#pragma unroll
      for (int kk = 0; kk < 8; ++kk) {
        float p0 = __expf(s[kk][0] - mn);
        float p1 = __expf(s[kk][1] - mn);
        float p2 = __expf(s[kk][2] - mn);
        float p3 = __expf(s[kk][3] - mn);
        s[kk][0] = p0; s[kk][1] = p1; s[kk][2] = p2; s[kk][3] = p3;
        lsum += (p0 + p1) + (p2 + p3);
      }
      lsum += __shfl_xor(lsum, 16);
      lsum += __shfl_xor(lsum, 32);

      if (skip) {
        lrow = lrow + lsum;
      } else {
        const float corr = __expf(mrow - mn);
        mrow = mn;
        lrow = lrow*corr + lsum;
        // o's q-index is l4*4+j: fetch corr for that q from the lane holding it
        float corrq[4];
#pragma unroll
        for (int j = 0; j < 4; ++j) corrq[j] = __shfl(corr, l4*4 + j, 16);
#pragma unroll
        for (int d = 0; d < 4; ++d)
#pragma unroll
          for (int j = 0; j < 4; ++j) o[d][j] *= corrq[j];
      }

      // ---- P^T regs -> Pls [q=l15][128 k], packed pairs, XOR-swizzled (256B rows) ----
      const unsigned pbase = (unsigned)(w*4096);
#pragma unroll
      for (int kk = 0; kk < 8; ++kk)
#pragma unroll
        for (int jp = 0; jp < 2; ++jp) {
          const unsigned v = (unsigned)f2bf(s[kk][jp*2]) | ((unsigned)f2bf(s[kk][jp*2+1]) << 16);
          const unsigned k = (unsigned)(kk*16 + l4*4 + jp*2);
          unsigned byte = (unsigned)l15*256u + ((k*2u) ^ xorb);
          *(unsigned*)((char*)Pls + pbase + byte) = v;
        }
      // same-wave cross-lane LDS handoff: order + completion, no workgroup barrier
      asm volatile("s_waitcnt lgkmcnt(0)" ::: "memory");

      // ---- PV ----
#pragma unroll
      for (int c = 0; c < 4; ++c) {
        const unsigned abyte = (unsigned)(l15*256) + (((unsigned)(c*64 + l4*16)) ^ xorb);
        const bf16x8 pa = *reinterpret_cast<const bf16x8*>((char*)Pls + pbase + abyte);
#pragma unroll
        for (int d = 0; d < 4; ++d) {
          const unsigned vbyte = (unsigned)((d*16 + l15)*256)
                               + (((unsigned)(c*64 + l4*16)) ^ xorb);
          const bf16x8 vb = *reinterpret_cast<const bf16x8*>((const char*)Vs[cur] + vbyte);
          o[d] = __builtin_amdgcn_mfma_f32_16x16x32_bf16(pa, vb, o[d], 0, 0, 0);
        }
      }

      // drain this wave's LDS reads, then next-tile staging loads; one barrier per tile
      asm volatile("s_waitcnt lgkmcnt(0)" ::: "memory");
      asm volatile("s_waitcnt vmcnt(0)" ::: "memory");
      __builtin_amdgcn_s_barrier();
    }

    float lrowq[4];
#pragma unroll
    for (int j = 0; j < 4; ++j) lrowq[j] = __shfl(lrow, l4*4 + j, 16);
#pragma unroll
    for (int d = 0; d < 4; ++d)
#pragma unroll
      for (int j = 0; j < 4; ++j) {
        const int row = qbase + w*16 + l4*4 + j;
        seqo[(size_t)(b*TT + row)*DD + h*64 + d*16 + l15] = f2bf(o[d][j] / lrowq[j]);
      }
  }
}

// ---------------- fused scan pass C: on-the-fly Jw/rd + BC prefix + scan + score ----------------
__global__ __launch_bounds__(64, 8)
void scan_passC(const unsigned short* __restrict__ P, const float* __restrict__ E,
                const float* __restrict__ decay_logits,
                const float* __restrict__ iter_mix, float* __restrict__ msc)
{
  __shared__ float Ls[SCH][12];   // [t][0..5]=jw, [6..11]=rl
  const int bid = blockIdx.x;            // 2048 = 32 s * 64 chunks
  const int s = bid >> 6, c = bid & (SNC-1);
  const int b_ = s >> 4, h = s & (HH-1);
  const int lane = threadIdx.x;

  if (lane < SCH) {
    const int t = c*SCH + lane;
    const size_t row = (size_t)(b_*TT + t)*LDP;
    float w1[4], w2[4], r1[4], r2[4];
    if (t > 0) load4bf(P + row - LDP + 3072 + h*4, w1);
    else { w1[0]=w1[1]=w1[2]=w1[3]=0.f; }
    load4bf(P + row + 3136 + h*4, w2);
    load4bf(P + row + 3200 + h*4, r1);
    load4bf(P + row + 3264 + h*4, r2);
    float wl[6], rl[6];
    ext6(w1, w2, wl);
    ext6(r1, r2, rl);
    Ls[lane][0]= wl[5]; Ls[lane][1]=-wl[4]; Ls[lane][2]= wl[3];
    Ls[lane][3]= wl[2]; Ls[lane][4]=-wl[1]; Ls[lane][5]= wl[0];
#pragma unroll
    for (int q = 0; q < 6; ++q) Ls[lane][6+q] = rl[q];
  }
  __syncthreads();

  const int i = lane & 7, j = lane >> 3;
  const bool valid = (i < 6) && (j < 6);
  const int ic = i < 6 ? i : 0, jc = j < 6 ? j : 0;
  const float d = sigmoidf_(decay_logits[h]);
  const float alpha = sigmoidf_(iter_mix[0]);

  // BC prefix: M(c) = sum_{c'<c} dL^{c-1-c'} E(c')
  float m = 0.f;
  if (valid) {
    const float dL = __powf(d, (float)SCH);
    for (int cp = 0; cp < c; ++cp)
      m = dL*m + E[((size_t)s*SNC + cp)*36 + j*6 + i];
  }

  for (int t = 0; t < SCH; ++t) {
    const float ai = Ls[t][ic];
    const float aj = Ls[t][jc];
    const float ri = Ls[t][6+ic];
    const float rj = Ls[t][6+jc];
    float part = valid ? ri*m : 0.f;            // y_j = sum_i r_i * M_ij
    part += __shfl_xor(part, 1);
    part += __shfl_xor(part, 2);
    part += __shfl_xor(part, 4);
    float contrib = (i == 0 && j < 6) ? part*((1.f-alpha)*rj + alpha*part) : 0.f;
    contrib += __shfl_xor(contrib, 8);
    contrib += __shfl_xor(contrib, 16);
    contrib += __shfl_xor(contrib, 32);
    if (lane == 0) msc[((size_t)b_*TT + c*SCH + t)*HH + h] = contrib;
    m = d*(m + ai*aj);
  }
}

// ---------------- gate + mix -> z (bf16); seqo is bf16 ----------------
__global__ __launch_bounds__(256, 4)
void combine_kernel(const unsigned short* __restrict__ seqo, const unsigned short* __restrict__ P,
                    const float* __restrict__ msc, const float* __restrict__ mem_scale,
                    unsigned short* __restrict__ zb)
{
  const int w = threadIdx.x >> 6, lane = threadIdx.x & 63;
  const int row = blockIdx.x*4 + w;
  float val = 0.f;
  if (lane < HH) {
    const float ms = msc[(size_t)row*HH + lane];
    const float gl = bf2f(P[(size_t)row*LDP + 4352 + lane]);
    val = sigmoidf_(ms*mem_scale[lane]) * sigmoidf_(gl);
  }
  val += __shfl_xor(val, 1);
  val += __shfl_xor(val, 2);
  val += __shfl_xor(val, 4);
  val += __shfl_xor(val, 8);
  const float g = __shfl(val, 0) * (1.0f/16.0f);
#pragma unroll
  for (int it = 0; it < 4; ++it) {
    const int dcol = it*256 + lane*4;
    const ushort4 sv = *(const ushort4*)&seqo[(size_t)row*DD + dcol];
    const ushort4 pv = *(const ushort4*)&P[(size_t)row*LDP + 3328 + dcol];
    ushort4 o;
    o.x = f2bf(bf2f(sv.x) + g*bf2f(pv.x));
    o.y = f2bf(bf2f(sv.y) + g*bf2f(pv.y));
    o.z = f2bf(bf2f(sv.z) + g*bf2f(pv.z));
    o.w = f2bf(bf2f(sv.w) + g*bf2f(pv.w));
    *(ushort4*)&zb[(size_t)row*DD + dcol] = o;
  }
}

// ---------------- launch ----------------
extern "C" void kernel_launch(void* const* d_in, const int* in_sizes, int n_in,
                              void* d_out, int out_size, void* d_ws, size_t ws_size,
                              hipStream_t stream)
{
  const float* x            = (const float*)d_in[0];
  const float* qkv_w        = (const float*)d_in[1];
  const float* qkv_b        = (const float*)d_in[2];
  const float* w1w          = (const float*)d_in[3];
  const float* w2w          = (const float*)d_in[4];
  const float* r1w          = (const float*)d_in[5];
  const float* r2w          = (const float*)d_in[6];
  const float* memv_w       = (const float*)d_in[7];
  const float* memv_b       = (const float*)d_in[8];
  const float* memg_w       = (const float*)d_in[9];
  const float* memg_b       = (const float*)d_in[10];
  const float* mem_scale    = (const float*)d_in[11];
  const float* iter_mix     = (const float*)d_in[12];
  const float* out_w        = (const float*)d_in[13];
  const float* out_b        = (const float*)d_in[14];
  const float* decay_logits = (const float*)d_in[15];

  char* ws = (char*)d_ws;
  unsigned short* xb   = (unsigned short*)(ws + 0);          //  8,388,608 B
  unsigned short* Wcat = (unsigned short*)(ws + 8388608);    // 11,042,816 B
  float*          bcat = (float*)         (ws + 19431424);   //     17,472 B
  unsigned short* P    = (unsigned short*)(ws + 19449088);   // 35,782,656 B
  unsigned short* VT   = (unsigned short*)(ws + 55231744);   //  8,388,608 B
  unsigned short* seqo = (unsigned short*)(ws + 63620352);   //  8,388,608 B (bf16)
  float*          E    = (float*)         (ws + 80397568);   //    294,912 B (2048*36*4)
  float*          msc  = (float*)         (ws + 83690752);   //    262,144 B
  unsigned short* zb   = xb;  // xb dead after GEMM1; reuse for z

  prep_all_kernel<<<9488, 256, 0, stream>>>(qkv_w, w1w, w2w, r1w, r2w, memv_w, memg_w, out_w,
                                            qkv_b, memv_b, memg_b, x, Wcat, bcat, xb);
  gemm_bt_kernel<false><<<dim3(32, 35), 256, 0, stream>>>(xb, 1024, Wcat, 1024, bcat,
                                                          P, LDP, 4368, 1024, VT);
  attn_kernel<<<1024, 256, 0, stream>>>(P, VT, seqo, decay_logits, E);
  scan_passC<<<2048, 64, 0, stream>>>(P, E, decay_logits, iter_mix, msc);
  combine_kernel<<<1024, 256, 0, stream>>>(seqo, P, msc, mem_scale, zb);
  gemm_bt_kernel<true><<<dim3(32, 8), 256, 0, stream>>>(zb, 1024, Wcat + (size_t)4368*1024, 1024,
                                                        out_b, d_out, 1024, 1024, 1024, nullptr);
}

// Round 18
// 166.050 us; speedup vs baseline: 1.0142x; 1.0142x over previous
//
#include <hip/hip_runtime.h>
#include <stdint.h>

#define TT 2048
#define DD 1024
#define HH 16
#define LDP 4368   // concat width: 3072 qkv | 64 w1 | 64 w2 | 64 r1 | 64 r2 | 1024 memv | 16 gate
#define SCH 64     // scan chunk length
#define SNC (TT/SCH)  // 32 chunks per sequence

using bf16x8 = __attribute__((ext_vector_type(8))) __bf16;
using u16x8  = __attribute__((ext_vector_type(8))) unsigned short;
using f32x4  = __attribute__((ext_vector_type(4))) float;

__device__ __forceinline__ float bf2f(unsigned short u){
  unsigned int x = ((unsigned int)u) << 16;
  return __builtin_bit_cast(float, x);
}
__device__ __forceinline__ unsigned short f2bf(float f){
  unsigned int x = __builtin_bit_cast(unsigned int, f);
  x += 0x7fffu + ((x >> 16) & 1u);
  return (unsigned short)(x >> 16);
}
__device__ __forceinline__ float sigmoidf_(float x){ return 1.0f/(1.0f+__expf(-x)); }

// global -> LDS direct (16B/lane). LDS base must be wave-uniform; HW adds lane*16.
__device__ __forceinline__ void gload_lds16(const void* g, void* l){
  auto gp = (const __attribute__((address_space(1))) unsigned int*)(uintptr_t)g;
  auto lp = (__attribute__((address_space(3))) unsigned int*)(unsigned int)(uintptr_t)l;
  __builtin_amdgcn_global_load_lds(gp, lp, 16, 0, 0);
}

// ---------------- exterior products + J6 map ----------------
__device__ __forceinline__ void ext6(const float* p, const float* q, float* L){
  L[0] = p[0]*q[1] - p[1]*q[0];
  L[1] = p[0]*q[2] - p[2]*q[0];
  L[2] = p[0]*q[3] - p[3]*q[0];
  L[3] = p[1]*q[2] - p[2]*q[1];
  L[4] = p[1]*q[3] - p[3]*q[1];
  L[5] = p[2]*q[3] - p[3]*q[2];
  const float n2 = L[0]*L[0]+L[1]*L[1]+L[2]*L[2]+L[3]*L[3]+L[4]*L[4]+L[5]*L[5];
  const float inv = 1.0f / fmaxf(sqrtf(n2), 1e-12f);
#pragma unroll
  for (int i = 0; i < 6; ++i) L[i] *= inv;
}

__device__ __forceinline__ void load4bf(const unsigned short* p, float* o){
  const ushort4 u = *(const ushort4*)p;
  o[0] = bf2f(u.x); o[1] = bf2f(u.y); o[2] = bf2f(u.z); o[3] = bf2f(u.w);
}

// ---------------- fused weight prep + x conversion ----------------
__global__ void prep_all_kernel(const float* __restrict__ qkv_w, const float* __restrict__ w1w,
                                const float* __restrict__ w2w, const float* __restrict__ r1w,
                                const float* __restrict__ r2w, const float* __restrict__ memv_w,
                                const float* __restrict__ memg_w, const float* __restrict__ out_w,
                                const float* __restrict__ qkv_b, const float* __restrict__ memv_b,
                                const float* __restrict__ memg_b, const float* __restrict__ x,
                                unsigned short* __restrict__ Wcat, float* __restrict__ bcat,
                                unsigned short* __restrict__ xb)
{
  const int blk = blockIdx.x;
  if (blk < 5392) {
    const int idx = blk*256 + threadIdx.x;
    {
      const int row = idx >> 8, c4 = (idx & 255)*4;
      const float* src; int r;
      if      (row < 3072) { src = qkv_w;  r = row; }
      else if (row < 3136) { src = w1w;    r = row-3072; }
      else if (row < 3200) { src = w2w;    r = row-3136; }
      else if (row < 3264) { src = r1w;    r = row-3200; }
      else if (row < 3328) { src = r2w;    r = row-3264; }
      else if (row < 4352) { src = memv_w; r = row-3328; }
      else if (row < 4368) { src = memg_w; r = row-4352; }
      else                 { src = out_w;  r = row-4368; }
      const float4 v = *(const float4*)(src + (size_t)r*1024 + c4);
      ushort4 o; o.x=f2bf(v.x); o.y=f2bf(v.y); o.z=f2bf(v.z); o.w=f2bf(v.w);
      *(ushort4*)(Wcat + (size_t)row*1024 + c4) = o;
    }
    if (idx < 4368) {
      float v;
      if      (idx < 3072) v = qkv_b[idx];
      else if (idx < 3328) v = 0.f;
      else if (idx < 4352) v = memv_b[idx-3328];
      else                 v = memg_b[idx-4352];
      bcat[idx] = v;
    }
  } else {
    const int idx = (blk - 5392)*256 + threadIdx.x;   // 4096*256 exact, 4 elems each
    const float4 v = ((const float4*)x)[idx];
    ushort4 o; o.x=f2bf(v.x); o.y=f2bf(v.y); o.z=f2bf(v.z); o.w=f2bf(v.w);
    ((ushort4*)xb)[idx] = o;
  }
}

// ---------------- GEMM: C[M,N] = A[M,K] * Bt[N,K]^T + bias ----------------
// 3-buffer (48KB), counted vmcnt(4) steady-state (round-9-proven).
// bf16 path: epilogue staged through LDS (row-XOR-swizzled) for coalesced 16B stores.
// V-column tiles (n0 in [2048,3072), VTout != null) store TRANSPOSED to VT instead of P.
template<bool OUTF32>
__global__ __launch_bounds__(256, 3)
void gemm_bt_kernel(const unsigned short* __restrict__ A, int lda,
                    const unsigned short* __restrict__ Bt, int ldb,
                    const float* __restrict__ bias,
                    void* __restrict__ Cout, int ldc, int N, int K,
                    unsigned short* __restrict__ VTout)
{
  __shared__ unsigned short smem[24576];   // A: 3 bufs @ 8KB | B: 3 bufs @ 8KB (byte 24576+)
  const int tid = threadIdx.x;
  const int w = tid >> 6, lane = tid & 63;
  const int l15 = lane & 15, l4 = lane >> 4;
  const int m0 = blockIdx.x * 128;
  const int n0 = blockIdx.y * 128;
  const int wr = (w >> 1) * 64, wc = (w & 1) * 64;

  const f32x4 zero = {0.f,0.f,0.f,0.f};
  f32x4 acc[4][4];
#pragma unroll
  for (int i = 0; i < 4; ++i)
#pragma unroll
    for (int j = 0; j < 4; ++j) acc[i][j] = zero;

  const int srow = lane >> 2;
  const int k8   = (lane & 3) * 8;

  auto stage = [&](int k0, int buf) {
#pragma unroll
    for (int q = 0; q < 4; ++q) {
      const int c = q*4 + w;                 // 0..15 chunk of 1KB
      const int rloc = (c & 7)*16 + srow;
      if (c < 8) {
        gload_lds16(A + (size_t)(m0 + rloc)*lda + k0 + k8,
                    (char*)smem + buf*8192 + (c&7)*1024);
      } else {
        int nrow = n0 + rloc; if (nrow >= N) nrow = N - 1;
        gload_lds16(Bt + (size_t)nrow*ldb + k0 + k8,
                    (char*)smem + 24576 + buf*8192 + (c&7)*1024);
      }
    }
  };

  stage(0, 0);
  if (K > 32) stage(32, 1);

  int ti = 0;
  for (int k0 = 0; k0 < K; k0 += 32, ++ti) {
    // stage(ti) must be retired; stage(ti+1) (4 loads/lane) may remain in flight
    if (k0 + 32 < K) { asm volatile("s_waitcnt vmcnt(4)" ::: "memory"); }
    else             { asm volatile("s_waitcnt vmcnt(0)" ::: "memory"); }
    __builtin_amdgcn_s_barrier();
    // overwrites buf (ti-1)%3: its readers issued MFMAs (lgkm-drained) before this barrier
    if (k0 + 64 < K) stage(k0 + 64, (ti + 2) % 3);

    const int cur = ti % 3;
    bf16x8 af[4], bfr[4];
#pragma unroll
    for (int i = 0; i < 4; ++i) {
      af[i]  = *reinterpret_cast<const bf16x8*>((const char*)smem + cur*8192
                 + (wr + i*16 + l15)*64 + l4*16);
      bfr[i] = *reinterpret_cast<const bf16x8*>((const char*)smem + 24576 + cur*8192
                 + (wc + i*16 + l15)*64 + l4*16);
    }
#pragma unroll
    for (int i = 0; i < 4; ++i)
#pragma unroll
      for (int j = 0; j < 4; ++j)
        acc[i][j] = __builtin_amdgcn_mfma_f32_16x16x32_bf16(af[i], bfr[j], acc[i][j], 0, 0, 0);
  }

  if (OUTF32) {
#pragma unroll
    for (int i = 0; i < 4; ++i) {
      const int rowb = m0 + wr + i*16 + l4*4;
#pragma unroll
      for (int j = 0; j < 4; ++j) {
        const int col = n0 + wc + j*16 + l15;
        if (col < N) {
          const float bv = bias ? bias[col] : 0.0f;
#pragma unroll
          for (int r = 0; r < 4; ++r)
            ((float*)Cout)[(size_t)(rowb + r)*ldc + col] = acc[i][j][r] + bv;
        }
      }
    }
  } else {
    // all waves' LDS reads retired before smem is repurposed for the C tile
    __syncthreads();
    const bool isV = (VTout != nullptr) && (n0 >= 2048) && (n0 < 3072);
    // stage C tile (+bias) into smem as [128][128] bf16, row-XOR-swizzled:
    // byte(row,col) = row*256 + ((col*2) ^ ((row&15)<<4))
#pragma unroll
    for (int i = 0; i < 4; ++i) {
      const int rloc = wr + i*16 + l4*4;
#pragma unroll
      for (int j = 0; j < 4; ++j) {
        const int col = wc + j*16 + l15;
        const float bv = bias ? bias[n0 + col] : 0.0f;
#pragma unroll
        for (int r = 0; r < 4; ++r) {
          const int row = rloc + r;
          const unsigned byte = (unsigned)row*256u
                              + (((unsigned)col*2u) ^ (((unsigned)row & 15u) << 4));
          *(unsigned short*)((char*)smem + byte) = f2bf(acc[i][j][r] + bv);
        }
      }
    }
    __syncthreads();
    if (!isV) {
#pragma unroll
      for (int p = 0; p < 8; ++p) {
        const int idx = p*256 + tid;          // 0..2047
        const int row = idx >> 4;             // 0..127
        const int c8  = (idx & 15) * 8;       // element 0..120
        if (n0 + c8 + 8 <= N) {
          // element c8's byte offset is c8*2 (16-aligned); swizzle preserves 16B blocks
          const unsigned byte = (unsigned)row*256u
                              + (((unsigned)(c8*2)) ^ (((unsigned)row & 15u) << 4));
          *(u16x8*)((unsigned short*)Cout + (size_t)(m0 + row)*ldc + n0 + c8) =
              *(const u16x8*)((const char*)smem + byte);
        }
      }
    } else {
      // transposed store: VT[vbase + d2][t0 + tl] = tile[tl][d2], t0 = within-batch offset
      const int vbase = ((m0 >> 11)*HH + ((n0 - 2048) >> 6)) * 64;
      const int t0 = m0 & (TT - 1);
      for (int it = 0; it < 64; ++it) {
        const int i2 = it*256 + tid;        // 0..16383
        const int d2 = i2 >> 7;             // 0..127  (tile column)
        const int tl = i2 & 127;            // 0..127  (tile row = t offset)
        const unsigned byte = (unsigned)tl*256u
                            + (((unsigned)d2*2u) ^ (((unsigned)tl & 15u) << 4));
        VTout[(size_t)(vbase + d2)*TT + t0 + tl] =
            *(const unsigned short*)((const char*)smem + byte);
      }
    }
  }
}

// ---------------- flash attention (+ fused scanA blocks) ----------------
// Blocks [0,512): paired q-tiles {pi,31-pi}, swapped-QK, KVBLK=128, XCD-grouped (round-15).
// Blocks [512,768): scanA — 4 chunks per block, one per wave (per-wave LDS overlay on Ks).
// seqo is written as bf16.
__global__ __launch_bounds__(256, 2)
void attn_kernel(const unsigned short* __restrict__ P,
                 const unsigned short* __restrict__ VT,
                 unsigned short* __restrict__ seqo,
                 const float* __restrict__ decay_logits,
                 float* __restrict__ E)
{
  __shared__ unsigned short Ks[2][128*64];   // [k-row][64 d], rows XOR-swizzled
  __shared__ unsigned short Vs[2][64*128];   // [d-row][128 k], rows XOR-swizzled
  __shared__ unsigned short Pls[4][16*128];  // per-wave [q][128 k], XOR-swizzled

  const int tid = threadIdx.x;
  const int w = tid >> 6, lane = tid & 63;
  const int l15 = lane & 15, l4 = lane >> 4;

  if (blockIdx.x >= 512) {
    // ---------- scanA: per-chunk E (one chunk per wave) ----------
    float* jwS = (float*)Ks + (size_t)w * SCH * 6;   // per-wave [SCH][6] overlay
    const int chunk = (blockIdx.x - 512)*4 + w;      // 0..1023 = 32 s * 32 chunks
    const int s = chunk >> 5, c = chunk & (SNC-1);
    const int b_ = s >> 4, h = s & (HH-1);
    {
      const int t = c*SCH + lane;
      const size_t row = (size_t)(b_*TT + t)*LDP;
      float w1[4], w2[4];
      if (t > 0) load4bf(P + row - LDP + 3072 + h*4, w1);
      else { w1[0]=w1[1]=w1[2]=w1[3]=0.f; }
      load4bf(P + row + 3136 + h*4, w2);
      float wl[6];
      ext6(w1, w2, wl);
      jwS[lane*6+0]= wl[5]; jwS[lane*6+1]=-wl[4]; jwS[lane*6+2]= wl[3];
      jwS[lane*6+3]= wl[2]; jwS[lane*6+4]=-wl[1]; jwS[lane*6+5]= wl[0];
    }
    // same-wave LDS handoff (writes visible to this wave's lanes)
    asm volatile("s_waitcnt lgkmcnt(0)" ::: "memory");

    const int i = lane & 7, j = lane >> 3;
    const int ic = i < 6 ? i : 0, jc = j < 6 ? j : 0;
    const float d = sigmoidf_(decay_logits[h]);
    float e = 0.f;
    for (int t = 0; t < SCH; ++t)
      e = d*(e + jwS[t*6+ic]*jwS[t*6+jc]);
    if (i < 6 && j < 6) E[(size_t)chunk*36 + j*6 + i] = e;
    return;
  }

  // ---------- attention ----------
  // XCD-grouped decode (T1): n -> (pi, h, b); 4 (b,h) groups per XCD
  const int n = blockIdx.x;
  const int xcd = n & 7, slot = n >> 3;
  const int grp = slot >> 4, pi = slot & 15;
  const int g = grp*8 + xcd;
  const int h = g & 15, b = g >> 4;

  auto stage = [&](int kt, int bufsel) {
#pragma unroll
    for (int q2 = 0; q2 < 4; ++q2) {
      const int idx = q2*256 + tid;
      {
        // K tile: 128 rows x 128B; element d at byte (d*2)^((r&7)<<4)
        const int r = idx >> 3;                          // 0..127
        const int cb = ((idx & 7)*16) ^ ((r & 7) << 4);  // swizzled source column byte
        gload_lds16(P + (size_t)(b*TT + kt*128 + r)*LDP + 1024 + h*64 + (cb >> 1),
                    (char*)Ks[bufsel] + q2*4096 + w*1024);
      }
      {
        // V tile: 64 rows x 256B; element k at byte (k*2)^((r&7)<<4)
        const int r = idx >> 4;                          // 0..63
        const int cb = ((idx & 15)*16) ^ ((r & 7) << 4); // swizzled source column byte
        gload_lds16(VT + (size_t)((b*HH + h)*64 + r)*TT + kt*128 + (cb >> 1),
                    (char*)Vs[bufsel] + q2*4096 + w*1024);
      }
    }
  };

  const f32x4 zero = {0.f,0.f,0.f,0.f};
  const unsigned xorb = ((unsigned)(l15 & 7u)) << 4;

  for (int rep = 0; rep < 2; ++rep) {
    const int qt = rep == 0 ? pi : 31 - pi;
    const int qbase = qt * 64;
    const int qrow = qbase + w*16 + l15;   // this lane's q-row
    const int nt = (qt >> 1) + 1;          // ceil((qt+1)/2) 128-wide k-tiles

    bf16x8 qa[2];
    {
      const size_t base = (size_t)(b*TT + qbase + w*16 + l15)*LDP + h*64 + l4*8;
      qa[0] = *reinterpret_cast<const bf16x8*>(P + base);
      qa[1] = *reinterpret_cast<const bf16x8*>(P + base + 32);
    }

    f32x4 o[4];
#pragma unroll
    for (int d = 0; d < 4; ++d) o[d] = zero;
    float mrow = -1e30f;
    float lrow = 0.f;

    stage(0, 0);
    asm volatile("s_waitcnt vmcnt(0)" ::: "memory");
    __builtin_amdgcn_s_barrier();

    for (int kt = 0; kt < nt; ++kt) {
      const int cur = kt & 1;
      if (kt + 1 < nt) stage(kt + 1, cur ^ 1);   // loads fly under this iteration's compute

      // ---- QK^T swapped: s[kk] = S^T, lane holds k = kk*16 + l4*4 + j for q = qrow ----
      f32x4 s[8];
#pragma unroll
      for (int kk = 0; kk < 8; ++kk) {
        f32x4 a = zero;
#pragma unroll
        for (int c = 0; c < 2; ++c) {
          const unsigned kbyte = (unsigned)((kk*16 + l15)*128)
                               + (((unsigned)(c*64 + l4*16)) ^ xorb);
          const bf16x8 kb = *reinterpret_cast<const bf16x8*>((const char*)Ks[cur] + kbyte);
          a = __builtin_amdgcn_mfma_f32_16x16x32_bf16(kb, qa[c], a, 0, 0, 0);
        }
        s[kk] = a;
      }

      if (kt == nt - 1) {   // diagonal-spanning tile (always the last one)
#pragma unroll
        for (int kk = 0; kk < 8; ++kk)
#pragma unroll
          for (int j = 0; j < 4; ++j) {
            const int kcol = kt*128 + kk*16 + l4*4 + j;
            s[kk][j] = (kcol <= qrow) ? s[kk][j]*0.125f : -1e30f;
          }
      } else {
#pragma unroll
        for (int kk = 0; kk < 8; ++kk)
#pragma unroll
          for (int j = 0; j < 4; ++j) s[kk][j] *= 0.125f;
      }

      // ---- online softmax, lane-local row (row spread over 4 lanes: xor16/xor32) ----
      float am[8];
#pragma unroll
      for (int kk = 0; kk < 8; ++kk)
        am[kk] = fmaxf(fmaxf(s[kk][0], s[kk][1]), fmaxf(s[kk][2], s[kk][3]));
      float tmax = fmaxf(fmaxf(fmaxf(am[0], am[1]), fmaxf(am[2], am[3])),
                         fmaxf(fmaxf(am[4], am[5]), fmaxf(am[6], am[7])));
      tmax = fmaxf(tmax, __shfl_xor(tmax, 16));
      tmax = fmaxf(tmax, __shfl_xor(tmax, 32));
      // T13 exact fast-path: tmax<=mrow for ALL rows -> corr==1, no rescale needed
      const bool skip = (__all(tmax <= mrow) != 0);
      const float mn = skip ? mrow : fmaxf(mrow, tmax);
      float lsum = 0.f;
#pragma unroll
      for (int kk = 0; kk < 8; ++kk) {
        float p0 = __expf(s[kk][0] - mn);
        float p1 = __expf(s[kk][1] - mn);
        float p2 = __expf(s[kk][2] - mn);
        float p3 = __expf(s[kk][3] - mn);
        s[kk][0] = p0; s[kk][1] = p1; s[kk][2] = p2; s[kk][3] = p3;
        lsum += (p0 + p1) + (p2 + p3);
      }
      lsum += __shfl_xor(lsum, 16);
      lsum += __shfl_xor(lsum, 32);

      if (skip) {
        lrow = lrow + lsum;
      } else {
        const float corr = __expf(mrow - mn);
        mrow = mn;
        lrow = lrow*corr + lsum;
        // o's q-index is l4*4+j: fetch corr for that q from the lane holding it
        float corrq[4];
#pragma unroll
        for (int j = 0; j < 4; ++j) corrq[j] = __shfl(corr, l4*4 + j, 16);
#pragma unroll
        for (int d = 0; d < 4; ++d)
#pragma unroll
          for (int j = 0; j < 4; ++j) o[d][j] *= corrq[j];
      }

      // ---- P^T regs -> Pls [q=l15][128 k], packed pairs, XOR-swizzled (256B rows) ----
      const unsigned pbase = (unsigned)(w*4096);
#pragma unroll
      for (int kk = 0; kk < 8; ++kk)
#pragma unroll
        for (int jp = 0; jp < 2; ++jp) {
          const unsigned v = (unsigned)f2bf(s[kk][jp*2]) | ((unsigned)f2bf(s[kk][jp*2+1]) << 16);
          const unsigned k = (unsigned)(kk*16 + l4*4 + jp*2);
          unsigned byte = (unsigned)l15*256u + ((k*2u) ^ xorb);
          *(unsigned*)((char*)Pls + pbase + byte) = v;
        }
      // same-wave cross-lane LDS handoff: order + completion, no workgroup barrier
      asm volatile("s_waitcnt lgkmcnt(0)" ::: "memory");

      // ---- PV ----
#pragma unroll
      for (int c = 0; c < 4; ++c) {
        const unsigned abyte = (unsigned)(l15*256) + (((unsigned)(c*64 + l4*16)) ^ xorb);
        const bf16x8 pa = *reinterpret_cast<const bf16x8*>((char*)Pls + pbase + abyte);
#pragma unroll
        for (int d = 0; d < 4; ++d) {
          const unsigned vbyte = (unsigned)((d*16 + l15)*256)
                               + (((unsigned)(c*64 + l4*16)) ^ xorb);
          const bf16x8 vb = *reinterpret_cast<const bf16x8*>((const char*)Vs[cur] + vbyte);
          o[d] = __builtin_amdgcn_mfma_f32_16x16x32_bf16(pa, vb, o[d], 0, 0, 0);
        }
      }

      // drain this wave's LDS reads, then next-tile staging loads; one barrier per tile
      asm volatile("s_waitcnt lgkmcnt(0)" ::: "memory");
      asm volatile("s_waitcnt vmcnt(0)" ::: "memory");
      __builtin_amdgcn_s_barrier();
    }

    float lrowq[4];
#pragma unroll
    for (int j = 0; j < 4; ++j) lrowq[j] = __shfl(lrow, l4*4 + j, 16);
#pragma unroll
    for (int d = 0; d < 4; ++d)
#pragma unroll
      for (int j = 0; j < 4; ++j) {
        const int row = qbase + w*16 + l4*4 + j;
        seqo[(size_t)(b*TT + row)*DD + h*64 + d*16 + l15] = f2bf(o[d][j] / lrowq[j]);
      }
  }
}

// ---------------- fused scan pass C: on-the-fly Jw/rd + BC prefix + scan + score ----------------
__global__ __launch_bounds__(64, 8)
void scan_passC(const unsigned short* __restrict__ P, const float* __restrict__ E,
                const float* __restrict__ decay_logits,
                const float* __restrict__ iter_mix, float* __restrict__ msc)
{
  __shared__ float Ls[SCH][12];   // [t][0..5]=jw, [6..11]=rl
  const int bid = blockIdx.x;            // 1024
  const int s = bid >> 5, c = bid & (SNC-1);
  const int b_ = s >> 4, h = s & (HH-1);
  const int lane = threadIdx.x;

  {
    const int t = c*SCH + lane;
    const size_t row = (size_t)(b_*TT + t)*LDP;
    float w1[4], w2[4], r1[4], r2[4];
    if (t > 0) load4bf(P + row - LDP + 3072 + h*4, w1);
    else { w1[0]=w1[1]=w1[2]=w1[3]=0.f; }
    load4bf(P + row + 3136 + h*4, w2);
    load4bf(P + row + 3200 + h*4, r1);
    load4bf(P + row + 3264 + h*4, r2);
    float wl[6], rl[6];
    ext6(w1, w2, wl);
    ext6(r1, r2, rl);
    Ls[lane][0]= wl[5]; Ls[lane][1]=-wl[4]; Ls[lane][2]= wl[3];
    Ls[lane][3]= wl[2]; Ls[lane][4]=-wl[1]; Ls[lane][5]= wl[0];
#pragma unroll
    for (int q = 0; q < 6; ++q) Ls[lane][6+q] = rl[q];
  }
  __syncthreads();

  const int i = lane & 7, j = lane >> 3;
  const bool valid = (i < 6) && (j < 6);
  const int ic = i < 6 ? i : 0, jc = j < 6 ? j : 0;
  const float d = sigmoidf_(decay_logits[h]);
  const float alpha = sigmoidf_(iter_mix[0]);

  // BC prefix: M(c) = sum_{c'<c} dL^{c-1-c'} E(c')
  float m = 0.f;
  if (valid) {
    const float dL = __powf(d, (float)SCH);
    for (int cp = 0; cp < c; ++cp)
      m = dL*m + E[((size_t)s*SNC + cp)*36 + j*6 + i];
  }

  for (int t = 0; t < SCH; ++t) {
    const float ai = Ls[t][ic];
    const float aj = Ls[t][jc];
    const float ri = Ls[t][6+ic];
    const float rj = Ls[t][6+jc];
    float part = valid ? ri*m : 0.f;            // y_j = sum_i r_i * M_ij
    part += __shfl_xor(part, 1);
    part += __shfl_xor(part, 2);
    part += __shfl_xor(part, 4);
    float contrib = (i == 0 && j < 6) ? part*((1.f-alpha)*rj + alpha*part) : 0.f;
    contrib += __shfl_xor(contrib, 8);
    contrib += __shfl_xor(contrib, 16);
    contrib += __shfl_xor(contrib, 32);
    if (lane == 0) msc[((size_t)b_*TT + c*SCH + t)*HH + h] = contrib;
    m = d*(m + ai*aj);
  }
}

// ---------------- gate + mix -> z (bf16); seqo is bf16 ----------------
__global__ __launch_bounds__(256, 4)
void combine_kernel(const unsigned short* __restrict__ seqo, const unsigned short* __restrict__ P,
                    const float* __restrict__ msc, const float* __restrict__ mem_scale,
                    unsigned short* __restrict__ zb)
{
  const int w = threadIdx.x >> 6, lane = threadIdx.x & 63;
  const int row = blockIdx.x*4 + w;
  float val = 0.f;
  if (lane < HH) {
    const float ms = msc[(size_t)row*HH + lane];
    const float gl = bf2f(P[(size_t)row*LDP + 4352 + lane]);
    val = sigmoidf_(ms*mem_scale[lane]) * sigmoidf_(gl);
  }
  val += __shfl_xor(val, 1);
  val += __shfl_xor(val, 2);
  val += __shfl_xor(val, 4);
  val += __shfl_xor(val, 8);
  const float g = __shfl(val, 0) * (1.0f/16.0f);
#pragma unroll
  for (int it = 0; it < 4; ++it) {
    const int dcol = it*256 + lane*4;
    const ushort4 sv = *(const ushort4*)&seqo[(size_t)row*DD + dcol];
    const ushort4 pv = *(const ushort4*)&P[(size_t)row*LDP + 3328 + dcol];
    ushort4 o;
    o.x = f2bf(bf2f(sv.x) + g*bf2f(pv.x));
    o.y = f2bf(bf2f(sv.y) + g*bf2f(pv.y));
    o.z = f2bf(bf2f(sv.z) + g*bf2f(pv.z));
    o.w = f2bf(bf2f(sv.w) + g*bf2f(pv.w));
    *(ushort4*)&zb[(size_t)row*DD + dcol] = o;
  }
}

// ---------------- launch ----------------
extern "C" void kernel_launch(void* const* d_in, const int* in_sizes, int n_in,
                              void* d_out, int out_size, void* d_ws, size_t ws_size,
                              hipStream_t stream)
{
  const float* x            = (const float*)d_in[0];
  const float* qkv_w        = (const float*)d_in[1];
  const float* qkv_b        = (const float*)d_in[2];
  const float* w1w          = (const float*)d_in[3];
  const float* w2w          = (const float*)d_in[4];
  const float* r1w          = (const float*)d_in[5];
  const float* r2w          = (const float*)d_in[6];
  const float* memv_w       = (const float*)d_in[7];
  const float* memv_b       = (const float*)d_in[8];
  const float* memg_w       = (const float*)d_in[9];
  const float* memg_b       = (const float*)d_in[10];
  const float* mem_scale    = (const float*)d_in[11];
  const float* iter_mix     = (const float*)d_in[12];
  const float* out_w        = (const float*)d_in[13];
  const float* out_b        = (const float*)d_in[14];
  const float* decay_logits = (const float*)d_in[15];

  char* ws = (char*)d_ws;
  unsigned short* xb   = (unsigned short*)(ws + 0);          //  8,388,608 B
  unsigned short* Wcat = (unsigned short*)(ws + 8388608);    // 11,042,816 B
  float*          bcat = (float*)         (ws + 19431424);   //     17,472 B
  unsigned short* P    = (unsigned short*)(ws + 19449088);   // 35,782,656 B
  unsigned short* VT   = (unsigned short*)(ws + 55231744);   //  8,388,608 B
  unsigned short* seqo = (unsigned short*)(ws + 63620352);   //  8,388,608 B (bf16)
  float*          E    = (float*)         (ws + 80397568);   //    147,456 B
  float*          msc  = (float*)         (ws + 83690752);   //    262,144 B
  unsigned short* zb   = xb;  // xb dead after GEMM1; reuse for z

  prep_all_kernel<<<9488, 256, 0, stream>>>(qkv_w, w1w, w2w, r1w, r2w, memv_w, memg_w, out_w,
                                            qkv_b, memv_b, memg_b, x, Wcat, bcat, xb);
  gemm_bt_kernel<false><<<dim3(32, 35), 256, 0, stream>>>(xb, 1024, Wcat, 1024, bcat,
                                                          P, LDP, 4368, 1024, VT);
  attn_kernel<<<768, 256, 0, stream>>>(P, VT, seqo, decay_logits, E);
  scan_passC<<<1024, 64, 0, stream>>>(P, E, decay_logits, iter_mix, msc);
  combine_kernel<<<1024, 256, 0, stream>>>(seqo, P, msc, mem_scale, zb);
  gemm_bt_kernel<true><<<dim3(32, 8), 256, 0, stream>>>(zb, 1024, Wcat + (size_t)4368*1024, 1024,
                                                        out_b, d_out, 1024, 1024, 1024, nullptr);
}